// Round 2
// baseline (52073.053 us; speedup 1.0000x reference)
//
#include <hip/hip_runtime.h>
#include <cmath>

constexpr int kB = 32, kS = 32, kE = 512, kH = 8, kV = 10000, kNB = 4;
constexpr int kQ = 3 * kE;  // 1536

// ---------------- device scratch ----------------
__device__ float g_w[kB * kS];
__device__ float g_pe[kS * kE];
__device__ float g_Y[kB * kS * kE];
__device__ float g_qkvbuf[kNB][kB * kS * kQ];   // qkv per decoder block (qkv0 persistent across steps)
__device__ float g_actb[kNB][kB * kS * kE];     // act output per decoder block
__device__ float g_logits[kB * kV];
__device__ float g_U[kNB * kE * kH];
__device__ float g_a0[kNB * kH];
__device__ float g_G[kNB * kH * kE];
__device__ float g_c0[kNB * kE];

// ---------------- setup kernels ----------------
__global__ void onehot_k(float* __restrict__ out) {
    int i = blockIdx.x * 256 + threadIdx.x;
    if (i >= kB * kV) return;
    int b = i / kV, v = i - b * kV;
    out[(size_t)b * kS * kV + v] = (v == 0) ? 1.f : 0.f;
}

__global__ void pe_k(float* __restrict__ pe) {
    int i = blockIdx.x * 256 + threadIdx.x;  // < kS*kE
    int s = i >> 9, e = i & 511;
    int base = e & ~1;
    float div = expf((float)base * (-logf(10000.f) / (float)kE));
    float ang = (float)s * div;
    pe[i] = (e & 1) ? cosf(ang) : sinf(ang);
}

__global__ void compute_w_k(const float* __restrict__ noise, const float* __restrict__ W_in,
                            const float* __restrict__ b_in, float* __restrict__ w) {
    __shared__ float X[kB * kS], T[kB * kS];
    int tid = threadIdx.x;  // 1024
    X[tid] = noise[tid];
    __syncthreads();
    int r = tid >> 5, c = tid & 31;
    float acc = b_in[c];
    for (int k = 0; k < 32; ++k) acc = fmaf(X[r * 32 + k], W_in[k * 32 + c], acc);
    T[tid] = acc;
    __syncthreads();
    acc = b_in[32 + c];
    for (int k = 0; k < 32; ++k) acc = fmaf(T[r * 32 + k], W_in[1024 + k * 32 + c], acc);
    w[tid] = acc;
}

// Y row 0 = emb[0]+pe[0]; also qkv0 row 0. One block per batch.
__global__ __launch_bounds__(256) void initY_k(const float* __restrict__ emb,
                                               const float* __restrict__ pe,
                                               float* __restrict__ Y,
                                               const float* __restrict__ Wq0,
                                               const float* __restrict__ bq0,
                                               float* __restrict__ qkv0) {
    __shared__ float ys[kE];
    int b = blockIdx.x, tid = threadIdx.x;
    for (int j = tid; j < kE; j += 256) {
        float v = emb[j] + pe[j];
        Y[(size_t)(b * kS) * kE + j] = v;
        ys[j] = v;
    }
    __syncthreads();
#pragma unroll
    for (int m = 0; m < 6; ++m) {
        int j = tid + 256 * m;
        const float* Wc = Wq0 + (size_t)(j >> 9) * (kE * kE) + (j & 511);
        float acc = bq0[j];
        for (int k = 0; k < kE; ++k) acc = fmaf(ys[k], Wc[(size_t)k * kE], acc);
        qkv0[(size_t)(b * kS) * kQ + j] = acc;
    }
}

// Precompute reduced cross-attn operators (same as validated round-1 version).
__global__ __launch_bounds__(256) void precross_k(const float* __restrict__ Wca,
                                                  const float* __restrict__ bca,
                                                  float* __restrict__ U, float* __restrict__ a0,
                                                  float* __restrict__ G, float* __restrict__ c0) {
    int n = blockIdx.x;
    const float* Wq = Wca + (size_t)n * 4 * kE * kE;
    const float* Wk = Wq + kE * kE;
    const float* Wv = Wk + kE * kE;
    const float* Wo = Wv + kE * kE;
    const float* bq = bca + n * 4 * kE;
    const float* bv = bq + 2 * kE;
    const float* bo = bq + 3 * kE;
    __shared__ float ck[kE], cv[kE];
    int tid = threadIdx.x;
    for (int j = tid; j < kE; j += 256) {
        float s1 = 0.f, s2 = 0.f;
        for (int e = 0; e < kE; ++e) { s1 += Wk[e * kE + j]; s2 += Wv[e * kE + j]; }
        ck[j] = s1; cv[j] = s2;
    }
    __syncthreads();
    for (int p = tid; p < kE * kH; p += 256) {
        int e = p >> 3, h = p & 7;
        float acc = 0.f;
        for (int d = 0; d < 64; ++d) acc = fmaf(Wq[e * kE + h * 64 + d], ck[h * 64 + d], acc);
        U[n * kE * kH + p] = acc;
    }
    if (tid < kH) {
        float acc = 0.f;
        for (int d = 0; d < 64; ++d) acc = fmaf(bq[tid * 64 + d], ck[tid * 64 + d], acc);
        a0[n * kH + tid] = acc;
    }
    for (int p = tid; p < kH * kE; p += 256) {
        int h = p >> 9, j = p & 511;
        float acc = 0.f;
        for (int d = 0; d < 64; ++d) acc = fmaf(cv[h * 64 + d], Wo[(h * 64 + d) * kE + j], acc);
        G[n * kH * kE + p] = acc;
    }
    for (int j = tid; j < kE; j += 256) {
        float acc = bo[j];
        for (int e = 0; e < kE; ++e) acc = fmaf(bv[e], Wo[e * kE + j], acc);
        c0[n * kE + j] = acc;
    }
}

// ---------------- reduction helpers (block = 256 threads, 4 waves) ----------------
__device__ __forceinline__ void rowsum4(float v[4], float (*red)[4], float out[4]) {
    int lane = threadIdx.x & 63, wid = threadIdx.x >> 6;
#pragma unroll
    for (int i = 0; i < 4; ++i) {
        float s = v[i];
#pragma unroll
        for (int o = 32; o > 0; o >>= 1) s += __shfl_xor(s, o);
        v[i] = s;
    }
    if (lane == 0) { red[wid][0] = v[0]; red[wid][1] = v[1]; red[wid][2] = v[2]; red[wid][3] = v[3]; }
    __syncthreads();
#pragma unroll
    for (int i = 0; i < 4; ++i) out[i] = red[0][i] + red[1][i] + red[2][i] + red[3][i];
    __syncthreads();
}

// LayerNorm of 4 rows held as (acc0,acc1) per thread (cols j0,j1); writes dst rows.
__device__ __forceinline__ void ln4(float acc0[4], float acc1[4], const float* __restrict__ g,
                                    const float* __restrict__ bb, float (*dst)[kE],
                                    float (*red)[4], int j0, int j1) {
    float s[4], mean[4], var[4];
#pragma unroll
    for (int i = 0; i < 4; ++i) s[i] = acc0[i] + acc1[i];
    rowsum4(s, red, mean);
#pragma unroll
    for (int i = 0; i < 4; ++i) {
        mean[i] *= (1.f / (float)kE);
        acc0[i] -= mean[i]; acc1[i] -= mean[i];
        s[i] = acc0[i] * acc0[i] + acc1[i] * acc1[i];
    }
    rowsum4(s, red, var);
#pragma unroll
    for (int i = 0; i < 4; ++i) {
        float rstd = rsqrtf(var[i] * (1.f / (float)kE) + 1e-5f);
        dst[i][j0] = g[j0] * acc0[i] * rstd + bb[j0];
        dst[i][j1] = g[j1] * acc1[i] * rstd + bb[j1];
    }
}

// ---------------- fused decoder-block tail ----------------
// grid (kB, ceil(t/4)), 256 threads. Per block: 4 rows of one batch.
// attn -> proj+res+LN -> cross -> crossout+LN -> FF1 -> FF2+LN -> act (+qkv of NEXT block)
__global__ __launch_bounds__(256) void megatail_k(
    const float* __restrict__ qkv_cur, const float* __restrict__ in_res,
    const float* __restrict__ Wo, const float* __restrict__ bo,
    const float* __restrict__ g0, const float* __restrict__ lb0,
    const float* __restrict__ Um, const float* __restrict__ a0m,
    const float* __restrict__ Gm, const float* __restrict__ c0m,
    const float* __restrict__ g1, const float* __restrict__ lb1,
    const float* __restrict__ W1, const float* __restrict__ fb1,
    const float* __restrict__ W2, const float* __restrict__ fb2,
    const float* __restrict__ g2, const float* __restrict__ lb2,
    const float* __restrict__ wvec, float* __restrict__ act_out,
    const float* __restrict__ Wqn, const float* __restrict__ bqn,
    float* __restrict__ qkv_next, int t) {
    __shared__ float bufA[4][kE];
    __shared__ float bufB[4][kE];
    __shared__ float att_s[4][32];
    __shared__ float red[4][4];
    __shared__ float om_s[4][8];
    __shared__ float w_s[kS];

    const int b = blockIdx.x;
    const int r0 = blockIdx.y * 4;
    const int tid = threadIdx.x;
    const int lane = tid & 63, wid = tid >> 6;
    int rr[4]; bool valid[4];
#pragma unroll
    for (int i = 0; i < 4; ++i) {
        int r = r0 + i;
        valid[i] = (r < t);
        rr[i] = valid[i] ? r : (t - 1);
    }

    // stage Q rows (clamped) into bufB, and w
    for (int p = tid; p < 4 * kE; p += 256) {
        int i = p >> 9, d = p & 511;
        bufB[i][d] = qkv_cur[(size_t)(b * kS + rr[i]) * kQ + d];
    }
    if (tid < t) w_s[tid] = wvec[b * kS + tid];
    __syncthreads();

    // ---- self-attention: wave wid handles q-row rr[wid] ----
    for (int h = 0; h < kH; ++h) {
        float sc = -3.0e38f;
        if (lane < t) {
            const float* Kr = qkv_cur + (size_t)(b * kS + lane) * kQ + kE + h * 64;
            float a = 0.f;
#pragma unroll
            for (int d4 = 0; d4 < 16; ++d4) {
                const float4 kv = *(const float4*)(Kr + d4 * 4);
                const float4 qv = *(const float4*)(&bufB[wid][h * 64 + d4 * 4]);
                a = fmaf(qv.x, kv.x, a); a = fmaf(qv.y, kv.y, a);
                a = fmaf(qv.z, kv.z, a); a = fmaf(qv.w, kv.w, a);
            }
            sc = a * 0.125f;
        }
        float m = sc;
#pragma unroll
        for (int o = 32; o > 0; o >>= 1) m = fmaxf(m, __shfl_xor(m, o));
        float e = (lane < t) ? expf(sc - m) : 0.f;
        float ss = e;
#pragma unroll
        for (int o = 32; o > 0; o >>= 1) ss += __shfl_xor(ss, o);
        if (lane < t) att_s[wid][lane] = e / ss;
        float acc = 0.f;
        const float* Vb = qkv_cur + (size_t)(b * kS) * kQ + 2 * kE + h * 64 + lane;
        for (int k = 0; k < t; ++k) acc = fmaf(att_s[wid][k], Vb[(size_t)k * kQ], acc);
        bufA[wid][h * 64 + lane] = acc;
    }
    __syncthreads();

    const int j0 = tid * 2, j1 = j0 + 1;

    // ---- proj + residual + LN -> bufB (h) ----
    {
        float acc0[4], acc1[4];
#pragma unroll
        for (int i = 0; i < 4; ++i) {
            const float* res = in_res + (size_t)(b * kS + rr[i]) * kE;
            acc0[i] = bo[j0] + res[j0];
            acc1[i] = bo[j1] + res[j1];
        }
#pragma unroll 4
        for (int k = 0; k < kE; ++k) {
            const float2 wv = *(const float2*)(Wo + (size_t)k * kE + j0);
#pragma unroll
            for (int i = 0; i < 4; ++i) {
                float av = bufA[i][k];
                acc0[i] = fmaf(av, wv.x, acc0[i]);
                acc1[i] = fmaf(av, wv.y, acc1[i]);
            }
        }
        ln4(acc0, acc1, g0, lb0, bufB, red, j0, j1);
    }
    __syncthreads();

    // ---- reduced cross-attn: alpha, omega ----
    if (tid < 32) {
        int i = tid >> 3, h = tid & 7;
        float a = a0m[h];
        for (int e = 0; e < kE; ++e) a = fmaf(bufB[i][e], Um[e * kH + h], a);
        a *= 0.125f;
        float mm = -3.0e38f;
        for (int s = 0; s < t; ++s) mm = fmaxf(mm, a * w_s[s]);
        float se = 0.f, sw = 0.f;
        for (int s = 0; s < t; ++s) {
            float ex = expf(a * w_s[s] - mm);
            se += ex;
            sw = fmaf(ex, w_s[s], sw);
        }
        om_s[i][h] = sw / se;
    }
    __syncthreads();

    // ---- crossout + residual + LN -> bufA (h2) ----
    {
        float acc0[4], acc1[4];
#pragma unroll
        for (int i = 0; i < 4; ++i) {
            float v0 = c0m[j0] + bufB[i][j0];
            float v1 = c0m[j1] + bufB[i][j1];
#pragma unroll
            for (int h = 0; h < kH; ++h) {
                float o = om_s[i][h];
                v0 = fmaf(o, Gm[h * kE + j0], v0);
                v1 = fmaf(o, Gm[h * kE + j1], v1);
            }
            acc0[i] = v0; acc1[i] = v1;
        }
        ln4(acc0, acc1, g1, lb1, bufA, red, j0, j1);
    }
    __syncthreads();

    // ---- FF1 (relu) -> bufB ----
    {
        float acc0[4], acc1[4];
#pragma unroll
        for (int i = 0; i < 4; ++i) { acc0[i] = fb1[j0]; acc1[i] = fb1[j1]; }
#pragma unroll 4
        for (int k = 0; k < kE; ++k) {
            const float2 wv = *(const float2*)(W1 + (size_t)k * kE + j0);
#pragma unroll
            for (int i = 0; i < 4; ++i) {
                float av = bufA[i][k];
                acc0[i] = fmaf(av, wv.x, acc0[i]);
                acc1[i] = fmaf(av, wv.y, acc1[i]);
            }
        }
        __syncthreads();  // all FF1 reads of bufA done; (bufB last read was crossout accum, already fenced)
#pragma unroll
        for (int i = 0; i < 4; ++i) {
            bufB[i][j0] = fmaxf(acc0[i], 0.f);
            bufB[i][j1] = fmaxf(acc1[i], 0.f);
        }
    }
    __syncthreads();

    // ---- FF2 + residual(h2) + LN -> bufA (act) ----
    {
        float acc0[4], acc1[4];
#pragma unroll
        for (int i = 0; i < 4; ++i) {
            acc0[i] = fb2[j0] + bufA[i][j0];
            acc1[i] = fb2[j1] + bufA[i][j1];
        }
#pragma unroll 4
        for (int k = 0; k < kE; ++k) {
            const float2 wv = *(const float2*)(W2 + (size_t)k * kE + j0);
#pragma unroll
            for (int i = 0; i < 4; ++i) {
                float av = bufB[i][k];
                acc0[i] = fmaf(av, wv.x, acc0[i]);
                acc1[i] = fmaf(av, wv.y, acc1[i]);
            }
        }
        ln4(acc0, acc1, g2, lb2, bufA, red, j0, j1);
    }
    __syncthreads();

    // write act to global
#pragma unroll
    for (int i = 0; i < 4; ++i)
        if (valid[i]) {
            float* dst = act_out + (size_t)(b * kS + r0 + i) * kE;
            dst[j0] = bufA[i][j0];
            dst[j1] = bufA[i][j1];
        }

    // ---- QKV projection for the NEXT decoder block ----
    if (Wqn != nullptr) {
        const float* Wc[6];
        float acc[4][6];
#pragma unroll
        for (int m = 0; m < 6; ++m) {
            int j = tid + 256 * m;
            Wc[m] = Wqn + (size_t)(j >> 9) * (kE * kE) + (j & 511);
            float bv = bqn[j];
#pragma unroll
            for (int i = 0; i < 4; ++i) acc[i][m] = bv;
        }
#pragma unroll 2
        for (int k = 0; k < kE; ++k) {
            float av[4];
#pragma unroll
            for (int i = 0; i < 4; ++i) av[i] = bufA[i][k];
#pragma unroll
            for (int m = 0; m < 6; ++m) {
                float wv = Wc[m][(size_t)k * kE];
#pragma unroll
                for (int i = 0; i < 4; ++i) acc[i][m] = fmaf(av[i], wv, acc[i][m]);
            }
        }
#pragma unroll
        for (int i = 0; i < 4; ++i)
            if (valid[i]) {
                float* dst = qkv_next + (size_t)(b * kS + r0 + i) * kQ;
#pragma unroll
                for (int m = 0; m < 6; ++m) dst[tid + 256 * m] = acc[i][m];
            }
    }
}

// ---------------- logits: grid (kB, 4), 2500 cols per block ----------------
__global__ __launch_bounds__(256) void logits_k(const float* __restrict__ act3,
                                                const float* __restrict__ softW,
                                                const float* __restrict__ softb,
                                                float* __restrict__ logits, int tokm1) {
    __shared__ float xs[kE];
    int b = blockIdx.x, q = blockIdx.y, tid = threadIdx.x;
    const float* xrow = act3 + (size_t)(b * kS + tokm1) * kE;
    xs[tid] = xrow[tid];
    xs[tid + 256] = xrow[tid + 256];
    __syncthreads();
    const int jb = q * 2500;
    float acc[10];
#pragma unroll
    for (int m = 0; m < 10; ++m) {
        int c = tid + 256 * m;
        acc[m] = (c < 2500) ? softb[jb + c] : 0.f;
    }
#pragma unroll 2
    for (int k = 0; k < kE; ++k) {
        float xv = xs[k];
        const float* Wr = softW + (size_t)k * kV + jb + tid;
#pragma unroll
        for (int m = 0; m < 10; ++m) {
            if (tid + 256 * m < 2500) acc[m] = fmaf(xv, Wr[256 * m], acc[m]);
        }
    }
#pragma unroll
    for (int m = 0; m < 10; ++m) {
        int c = tid + 256 * m;
        if (c < 2500) logits[(size_t)b * kV + jb + c] = acc[m];
    }
}

// ---------------- softmax + argmax + probs + Y row + qkv0 row ----------------
__global__ __launch_bounds__(256) void softargmax_k(const float* __restrict__ logits,
                                                    float* __restrict__ outp,
                                                    const float* __restrict__ emb,
                                                    const float* __restrict__ pe_t,
                                                    float* __restrict__ Y,
                                                    const float* __restrict__ Wq0,
                                                    const float* __restrict__ bq0,
                                                    float* __restrict__ qkv0, int tok) {
    __shared__ float redf[4];
    __shared__ int redi[4];
    __shared__ float ys[kE];
    int b = blockIdx.x, tid = threadIdx.x;
    const float* lg = logits + (size_t)b * kV;
    float m = -3.4e38f;
    int mi = 0;
    for (int j = tid; j < kV; j += 256) {
        float v = lg[j];
        if (v > m) { m = v; mi = j; }
    }
#pragma unroll
    for (int o = 32; o > 0; o >>= 1) {
        float m2 = __shfl_xor(m, o);
        int i2 = __shfl_xor(mi, o);
        if (m2 > m || (m2 == m && i2 < mi)) { m = m2; mi = i2; }
    }
    int wid = tid >> 6;
    if ((tid & 63) == 0) { redf[wid] = m; redi[wid] = mi; }
    __syncthreads();
    m = redf[0]; mi = redi[0];
#pragma unroll
    for (int wv = 1; wv < 4; ++wv) {
        if (redf[wv] > m || (redf[wv] == m && redi[wv] < mi)) { m = redf[wv]; mi = redi[wv]; }
    }
    __syncthreads();
    float ssum = 0.f;
    for (int j = tid; j < kV; j += 256) ssum += expf(lg[j] - m);
    {
#pragma unroll
        for (int o = 32; o > 0; o >>= 1) ssum += __shfl_xor(ssum, o);
        if ((tid & 63) == 0) redf[wid] = ssum;
        __syncthreads();
        ssum = redf[0] + redf[1] + redf[2] + redf[3];
    }
    float inv = 1.f / ssum;
    float* orow = outp + (size_t)b * ((size_t)kS * kV);
    for (int j = tid; j < kV; j += 256) orow[j] = expf(lg[j] - m) * inv;
    // new Y row
    const float* erow = emb + (size_t)mi * kE;
    float* yrow = Y + (size_t)(b * kS + tok) * kE;
    for (int j = tid; j < kE; j += 256) {
        float v = erow[j] + pe_t[j];
        yrow[j] = v;
        ys[j] = v;
    }
    __syncthreads();
    // qkv0 for the new row (cached: Y rows are immutable)
#pragma unroll
    for (int mq = 0; mq < 6; ++mq) {
        int j = tid + 256 * mq;
        const float* Wc = Wq0 + (size_t)(j >> 9) * (kE * kE) + (j & 511);
        float acc = bq0[j];
        for (int k = 0; k < kE; ++k) acc = fmaf(ys[k], Wc[(size_t)k * kE], acc);
        qkv0[(size_t)(b * kS + tok) * kQ + j] = acc;
    }
}

// ---------------- host ----------------
extern "C" void kernel_launch(void* const* d_in, const int* in_sizes, int n_in, void* d_out,
                              int out_size, void* d_ws, size_t ws_size, hipStream_t stream) {
    const float* noise = (const float*)d_in[0];
    const float* W_in = (const float*)d_in[1];
    const float* b_in = (const float*)d_in[2];
    const float* emb = (const float*)d_in[3];
    const float* Wsa = (const float*)d_in[4];
    const float* bsa = (const float*)d_in[5];
    const float* Wca = (const float*)d_in[6];
    const float* bca = (const float*)d_in[7];
    const float* Wff = (const float*)d_in[8];
    const float* bff = (const float*)d_in[9];
    const float* ln_g = (const float*)d_in[10];
    const float* ln_b = (const float*)d_in[11];
    const float* softW = (const float*)d_in[12];
    const float* softb = (const float*)d_in[13];
    float* out = (float*)d_out;
    (void)d_ws; (void)ws_size; (void)in_sizes; (void)n_in; (void)out_size;

    float *w_, *pe_, *Y_, *qkvb_, *actb_, *lg_, *U_, *a0_, *G_, *c0_;
    hipGetSymbolAddress((void**)&w_, HIP_SYMBOL(g_w));
    hipGetSymbolAddress((void**)&pe_, HIP_SYMBOL(g_pe));
    hipGetSymbolAddress((void**)&Y_, HIP_SYMBOL(g_Y));
    hipGetSymbolAddress((void**)&qkvb_, HIP_SYMBOL(g_qkvbuf));
    hipGetSymbolAddress((void**)&actb_, HIP_SYMBOL(g_actb));
    hipGetSymbolAddress((void**)&lg_, HIP_SYMBOL(g_logits));
    hipGetSymbolAddress((void**)&U_, HIP_SYMBOL(g_U));
    hipGetSymbolAddress((void**)&a0_, HIP_SYMBOL(g_a0));
    hipGetSymbolAddress((void**)&G_, HIP_SYMBOL(g_G));
    hipGetSymbolAddress((void**)&c0_, HIP_SYMBOL(g_c0));

    float* qb[kNB];
    float* ab[kNB];
    for (int n = 0; n < kNB; ++n) {
        qb[n] = qkvb_ + (size_t)n * (kB * kS * kQ);
        ab[n] = actb_ + (size_t)n * (kB * kS * kE);
    }

    dim3 blk(256);
    hipLaunchKernelGGL(onehot_k, dim3((kB * kV + 255) / 256), blk, 0, stream, out);
    hipLaunchKernelGGL(pe_k, dim3(kS * kE / 256), blk, 0, stream, pe_);
    hipLaunchKernelGGL(compute_w_k, dim3(1), dim3(1024), 0, stream, noise, W_in, b_in, w_);
    hipLaunchKernelGGL(initY_k, dim3(kB), blk, 0, stream, emb, pe_, Y_, Wsa, bsa, qb[0]);
    hipLaunchKernelGGL(precross_k, dim3(kNB), blk, 0, stream, Wca, bca, U_, a0_, G_, c0_);

    for (int tok = 1; tok < kS; ++tok) {
        const int t = tok;
        const int nch = (t + 3) / 4;
        for (int n = 0; n < kNB; ++n) {
            const float* in_res = (n == 0) ? Y_ : ab[n - 1];
            const float* Wn = Wsa + (size_t)n * 4 * kE * kE;
            const float* bn = bsa + (size_t)n * 4 * kE;
            const float* Wf = Wff + (size_t)n * 2 * kE * kE;
            const float* bf = bff + (size_t)n * 2 * kE;
            const float* Wqn = (n < 3) ? (Wsa + (size_t)(n + 1) * 4 * kE * kE) : nullptr;
            const float* bqn = (n < 3) ? (bsa + (size_t)(n + 1) * 4 * kE) : bsa;
            float* qnext = (n < 3) ? qb[n + 1] : nullptr;
            hipLaunchKernelGGL(megatail_k, dim3(kB, nch), blk, 0, stream,
                               qb[n], in_res,
                               Wn + 3 * kE * kE, bn + 3 * kE,
                               ln_g + (size_t)(n * 3 + 0) * kE, ln_b + (size_t)(n * 3 + 0) * kE,
                               U_ + n * kE * kH, a0_ + n * kH, G_ + n * kH * kE, c0_ + n * kE,
                               ln_g + (size_t)(n * 3 + 1) * kE, ln_b + (size_t)(n * 3 + 1) * kE,
                               Wf, bf, Wf + kE * kE, bf + kE,
                               ln_g + (size_t)(n * 3 + 2) * kE, ln_b + (size_t)(n * 3 + 2) * kE,
                               w_, ab[n], Wqn, bqn, qnext, t);
        }
        hipLaunchKernelGGL(logits_k, dim3(kB, 4), blk, 0, stream, ab[3], softW, softb, lg_,
                           tok - 1);
        hipLaunchKernelGGL(softargmax_k, dim3(kB), blk, 0, stream, lg_,
                           out + (size_t)tok * kV, emb, pe_ + (size_t)tok * kE, Y_, Wsa, bsa,
                           qb[0], tok);
    }
}

// Round 3
// 33140.976 us; speedup vs baseline: 1.5713x; 1.5713x over previous
//
#include <hip/hip_runtime.h>
#include <cmath>

constexpr int kB = 32, kS = 32, kE = 512, kH = 8, kV = 10000, kNB = 4;
constexpr int kQ = 3 * kE;  // 1536
constexpr int ROWS = 8;     // rows per tail block

// ---------------- device scratch ----------------
__device__ float g_w[kB * kS];
__device__ float g_pe[kS * kE];
__device__ float g_Y[kB * kS * kE];
__device__ float g_qkvbuf[kNB][kB * kS * kQ];
__device__ float g_actb[kNB][kB * kS * kE];
__device__ float g_logits[kB * kV];
__device__ float g_U[kNB * kE * kH];
__device__ float g_a0[kNB * kH];
__device__ float g_G[kNB * kH * kE];
__device__ float g_c0[kNB * kE];

// ---------------- setup kernels ----------------
__global__ void onehot_k(float* __restrict__ out) {
    int i = blockIdx.x * 256 + threadIdx.x;
    if (i >= kB * kV) return;
    int b = i / kV, v = i - b * kV;
    out[(size_t)b * kS * kV + v] = (v == 0) ? 1.f : 0.f;
}

__global__ void pe_k(float* __restrict__ pe) {
    int i = blockIdx.x * 256 + threadIdx.x;  // < kS*kE
    int s = i >> 9, e = i & 511;
    int base = e & ~1;
    float div = expf((float)base * (-logf(10000.f) / (float)kE));
    float ang = (float)s * div;
    pe[i] = (e & 1) ? cosf(ang) : sinf(ang);
}

__global__ void compute_w_k(const float* __restrict__ noise, const float* __restrict__ W_in,
                            const float* __restrict__ b_in, float* __restrict__ w) {
    __shared__ float X[kB * kS], T[kB * kS];
    int tid = threadIdx.x;  // 1024
    X[tid] = noise[tid];
    __syncthreads();
    int r = tid >> 5, c = tid & 31;
    float acc = b_in[c];
    for (int k = 0; k < 32; ++k) acc = fmaf(X[r * 32 + k], W_in[k * 32 + c], acc);
    T[tid] = acc;
    __syncthreads();
    acc = b_in[32 + c];
    for (int k = 0; k < 32; ++k) acc = fmaf(T[r * 32 + k], W_in[1024 + k * 32 + c], acc);
    w[tid] = acc;
}

// Y row 0 = emb[0]+pe[0]; also qkv0 row 0. One block per batch.
__global__ __launch_bounds__(256) void initY_k(const float* __restrict__ emb,
                                               const float* __restrict__ pe,
                                               float* __restrict__ Y,
                                               const float* __restrict__ Wq0,
                                               const float* __restrict__ bq0,
                                               float* __restrict__ qkv0) {
    __shared__ float ys[kE];
    int b = blockIdx.x, tid = threadIdx.x;
    for (int j = tid; j < kE; j += 256) {
        float v = emb[j] + pe[j];
        Y[(size_t)(b * kS) * kE + j] = v;
        ys[j] = v;
    }
    __syncthreads();
#pragma unroll
    for (int m = 0; m < 6; ++m) {
        int j = tid + 256 * m;
        const float* Wc = Wq0 + (size_t)(j >> 9) * (kE * kE) + (j & 511);
        float acc = bq0[j];
        for (int k = 0; k < kE; ++k) acc = fmaf(ys[k], Wc[(size_t)k * kE], acc);
        qkv0[(size_t)(b * kS) * kQ + j] = acc;
    }
}

// Precompute reduced cross-attn operators.
__global__ __launch_bounds__(256) void precross_k(const float* __restrict__ Wca,
                                                  const float* __restrict__ bca,
                                                  float* __restrict__ U, float* __restrict__ a0,
                                                  float* __restrict__ G, float* __restrict__ c0) {
    int n = blockIdx.x;
    const float* Wq = Wca + (size_t)n * 4 * kE * kE;
    const float* Wk = Wq + kE * kE;
    const float* Wv = Wk + kE * kE;
    const float* Wo = Wv + kE * kE;
    const float* bq = bca + n * 4 * kE;
    const float* bv = bq + 2 * kE;
    const float* bo = bq + 3 * kE;
    __shared__ float ck[kE], cv[kE];
    int tid = threadIdx.x;
    for (int j = tid; j < kE; j += 256) {
        float s1 = 0.f, s2 = 0.f;
        for (int e = 0; e < kE; ++e) { s1 += Wk[e * kE + j]; s2 += Wv[e * kE + j]; }
        ck[j] = s1; cv[j] = s2;
    }
    __syncthreads();
    for (int p = tid; p < kE * kH; p += 256) {
        int e = p >> 3, h = p & 7;
        float acc = 0.f;
        for (int d = 0; d < 64; ++d) acc = fmaf(Wq[e * kE + h * 64 + d], ck[h * 64 + d], acc);
        U[n * kE * kH + p] = acc;
    }
    if (tid < kH) {
        float acc = 0.f;
        for (int d = 0; d < 64; ++d) acc = fmaf(bq[tid * 64 + d], ck[tid * 64 + d], acc);
        a0[n * kH + tid] = acc;
    }
    for (int p = tid; p < kH * kE; p += 256) {
        int h = p >> 9, j = p & 511;
        float acc = 0.f;
        for (int d = 0; d < 64; ++d) acc = fmaf(cv[h * 64 + d], Wo[(h * 64 + d) * kE + j], acc);
        G[n * kH * kE + p] = acc;
    }
    for (int j = tid; j < kE; j += 256) {
        float acc = bo[j];
        for (int e = 0; e < kE; ++e) acc = fmaf(bv[e], Wo[e * kE + j], acc);
        c0[n * kE + j] = acc;
    }
}

// ---------------- 8-row reductions ----------------
__device__ __forceinline__ void rowsum8(float v[ROWS], float (*red)[ROWS], float out[ROWS]) {
    int lane = threadIdx.x & 63, wid = threadIdx.x >> 6;
#pragma unroll
    for (int i = 0; i < ROWS; ++i) {
        float s = v[i];
#pragma unroll
        for (int o = 32; o > 0; o >>= 1) s += __shfl_xor(s, o);
        v[i] = s;
    }
    if (lane == 0) {
#pragma unroll
        for (int i = 0; i < ROWS; ++i) red[wid][i] = v[i];
    }
    __syncthreads();
#pragma unroll
    for (int i = 0; i < ROWS; ++i) out[i] = red[0][i] + red[1][i] + red[2][i] + red[3][i];
    __syncthreads();
}

// In-place LN of 8 rows held as (a0,a1) per thread (cols j0,j1).
__device__ __forceinline__ void ln8(float a0[ROWS], float a1[ROWS], const float* __restrict__ g,
                                    const float* __restrict__ bb, float (*red)[ROWS], int j0,
                                    int j1) {
    float s[ROWS], mean[ROWS], var[ROWS];
#pragma unroll
    for (int i = 0; i < ROWS; ++i) s[i] = a0[i] + a1[i];
    rowsum8(s, red, mean);
#pragma unroll
    for (int i = 0; i < ROWS; ++i) {
        mean[i] *= (1.f / (float)kE);
        a0[i] -= mean[i]; a1[i] -= mean[i];
        s[i] = a0[i] * a0[i] + a1[i] * a1[i];
    }
    rowsum8(s, red, var);
#pragma unroll
    for (int i = 0; i < ROWS; ++i) {
        float rstd = rsqrtf(var[i] * (1.f / (float)kE) + 1e-5f);
        a0[i] = g[j0] * a0[i] * rstd + bb[j0];
        a1[i] = g[j1] * a1[i] * rstd + bb[j1];
    }
}

// ---------------- fused tail: attn+proj+LN+cross+crossLN+FF1+FF2+LN ----------------
// grid (kB, ceil(t/8)), 256 threads. Weights streamed: Wo(1MB)+W1(1MB)+W2(1MB).
__global__ __launch_bounds__(256) void tail8_k(
    const float* __restrict__ qkv_cur, const float* __restrict__ in_res,
    const float* __restrict__ Wo, const float* __restrict__ bo,
    const float* __restrict__ g0, const float* __restrict__ lb0,
    const float* __restrict__ Um, const float* __restrict__ a0m,
    const float* __restrict__ Gm, const float* __restrict__ c0m,
    const float* __restrict__ g1, const float* __restrict__ lb1,
    const float* __restrict__ W1, const float* __restrict__ fb1,
    const float* __restrict__ W2, const float* __restrict__ fb2,
    const float* __restrict__ g2, const float* __restrict__ lb2,
    const float* __restrict__ wvec, float* __restrict__ act_out, int t) {
    __shared__ float bufA[ROWS][kE];   // 16KB
    __shared__ float Us[kE * kH];      // 16KB
    __shared__ float att_s[4][kS];
    __shared__ float red[4][ROWS];
    __shared__ float om_s[ROWS][kH];
    __shared__ float w_s[kS];

    const int b = blockIdx.x;
    const int r0 = blockIdx.y * ROWS;
    const int tid = threadIdx.x;
    const int lane = tid & 63, wid = tid >> 6;
    int rr[ROWS]; bool valid[ROWS];
#pragma unroll
    for (int i = 0; i < ROWS; ++i) {
        int r = r0 + i;
        valid[i] = (r < t);
        rr[i] = valid[i] ? r : (t - 1);
    }

    // stage Q rows, U, w
    for (int p = tid; p < ROWS * kE; p += 256) {
        int i = p >> 9, d = p & 511;
        bufA[i][d] = qkv_cur[(size_t)(b * kS + rr[i]) * kQ + d];
    }
    for (int p = tid; p < kE * kH; p += 256) Us[p] = Um[p];
    if (tid < t) w_s[tid] = wvec[b * kS + tid];
    __syncthreads();

    // ---- self-attention: wave wid handles rows wid, wid+4 ----
#pragma unroll
    for (int ii = 0; ii < 2; ++ii) {
        const int i = wid + 4 * ii;
        for (int h = 0; h < kH; ++h) {
            float sc = -3.0e38f;
            if (lane < t) {
                const float* Kr = qkv_cur + (size_t)(b * kS + lane) * kQ + kE + h * 64;
                float a = 0.f;
#pragma unroll
                for (int d4 = 0; d4 < 16; ++d4) {
                    const float4 kv = *(const float4*)(Kr + d4 * 4);
                    const float4 qv = *(const float4*)(&bufA[i][h * 64 + d4 * 4]);
                    a = fmaf(qv.x, kv.x, a); a = fmaf(qv.y, kv.y, a);
                    a = fmaf(qv.z, kv.z, a); a = fmaf(qv.w, kv.w, a);
                }
                sc = a * 0.125f;
            }
            float m = sc;
#pragma unroll
            for (int o = 32; o > 0; o >>= 1) m = fmaxf(m, __shfl_xor(m, o));
            float e = (lane < t) ? expf(sc - m) : 0.f;
            float ss = e;
#pragma unroll
            for (int o = 32; o > 0; o >>= 1) ss += __shfl_xor(ss, o);
            if (lane < t) att_s[wid][lane] = e / ss;
            float acc = 0.f;
            const float* Vb = qkv_cur + (size_t)(b * kS) * kQ + 2 * kE + h * 64 + lane;
            for (int k = 0; k < t; ++k) acc = fmaf(att_s[wid][k], Vb[(size_t)k * kQ], acc);
            bufA[i][h * 64 + lane] = acc;  // safe: Q[i] head-h slice dead after its score
        }
    }
    __syncthreads();

    const int j0 = tid * 2, j1 = j0 + 1;
    float a0r[ROWS], a1r[ROWS];

    // ---- proj + residual + LN -> h (bufA) ----
#pragma unroll
    for (int i = 0; i < ROWS; ++i) {
        const float* res = in_res + (size_t)(b * kS + rr[i]) * kE;
        a0r[i] = bo[j0] + res[j0];
        a1r[i] = bo[j1] + res[j1];
    }
#pragma unroll 4
    for (int k = 0; k < kE; ++k) {
        const float2 wv = *(const float2*)(Wo + (size_t)k * kE + j0);
#pragma unroll
        for (int i = 0; i < ROWS; ++i) {
            float av = bufA[i][k];
            a0r[i] = fmaf(av, wv.x, a0r[i]);
            a1r[i] = fmaf(av, wv.y, a1r[i]);
        }
    }
    ln8(a0r, a1r, g0, lb0, red, j0, j1);  // internal syncs fence the k-loop reads
#pragma unroll
    for (int i = 0; i < ROWS; ++i) { bufA[i][j0] = a0r[i]; bufA[i][j1] = a1r[i]; }
    __syncthreads();

    // ---- reduced cross-attn ----
    if (tid < ROWS * kH) {
        int i = tid >> 3, h = tid & 7;
        float a = a0m[h];
        for (int e = 0; e < kE; ++e) a = fmaf(bufA[i][e], Us[e * kH + h], a);
        a *= 0.125f;
        float mm = -3.0e38f;
        for (int s = 0; s < t; ++s) mm = fmaxf(mm, a * w_s[s]);
        float se = 0.f, sw = 0.f;
        for (int s = 0; s < t; ++s) {
            float ex = expf(a * w_s[s] - mm);
            se += ex;
            sw = fmaf(ex, w_s[s], sw);
        }
        om_s[i][h] = sw / se;
    }
    __syncthreads();

    // ---- crossout + residual + LN -> h2 (bufA) ----
#pragma unroll
    for (int i = 0; i < ROWS; ++i) {
        float v0 = c0m[j0] + bufA[i][j0];
        float v1 = c0m[j1] + bufA[i][j1];
#pragma unroll
        for (int h = 0; h < kH; ++h) {
            float o = om_s[i][h];
            v0 = fmaf(o, Gm[h * kE + j0], v0);
            v1 = fmaf(o, Gm[h * kE + j1], v1);
        }
        a0r[i] = v0; a1r[i] = v1;
    }
    ln8(a0r, a1r, g1, lb1, red, j0, j1);
#pragma unroll
    for (int i = 0; i < ROWS; ++i) { bufA[i][j0] = a0r[i]; bufA[i][j1] = a1r[i]; }
    __syncthreads();

    // ---- FF1 ----
#pragma unroll
    for (int i = 0; i < ROWS; ++i) { a0r[i] = fb1[j0]; a1r[i] = fb1[j1]; }
#pragma unroll 4
    for (int k = 0; k < kE; ++k) {
        const float2 wv = *(const float2*)(W1 + (size_t)k * kE + j0);
#pragma unroll
        for (int i = 0; i < ROWS; ++i) {
            float av = bufA[i][k];
            a0r[i] = fmaf(av, wv.x, a0r[i]);
            a1r[i] = fmaf(av, wv.y, a1r[i]);
        }
    }
    // save h2 residual (own cols) to regs
    float r0r[ROWS], r1r[ROWS];
#pragma unroll
    for (int i = 0; i < ROWS; ++i) { r0r[i] = bufA[i][j0]; r1r[i] = bufA[i][j1]; }
    __syncthreads();  // all FF1 k-loop reads done
#pragma unroll
    for (int i = 0; i < ROWS; ++i) {
        bufA[i][j0] = fmaxf(a0r[i], 0.f);
        bufA[i][j1] = fmaxf(a1r[i], 0.f);
    }
    __syncthreads();

    // ---- FF2 + residual + LN -> act ----
#pragma unroll
    for (int i = 0; i < ROWS; ++i) { a0r[i] = fb2[j0] + r0r[i]; a1r[i] = fb2[j1] + r1r[i]; }
#pragma unroll 4
    for (int k = 0; k < kE; ++k) {
        const float2 wv = *(const float2*)(W2 + (size_t)k * kE + j0);
#pragma unroll
        for (int i = 0; i < ROWS; ++i) {
            float av = bufA[i][k];
            a0r[i] = fmaf(av, wv.x, a0r[i]);
            a1r[i] = fmaf(av, wv.y, a1r[i]);
        }
    }
    ln8(a0r, a1r, g2, lb2, red, j0, j1);
#pragma unroll
    for (int i = 0; i < ROWS; ++i)
        if (valid[i]) {
            float* dst = act_out + (size_t)(b * kS + r0 + i) * kE;
            dst[j0] = a0r[i];
            dst[j1] = a1r[i];
        }
}

// ---------------- tiled fp32 GEMM (verified round-1): C = A@W + bias ----------------
__global__ __launch_bounds__(256) void gemm_k(const float* __restrict__ A,
                                              const float* __restrict__ W,
                                              const float* __restrict__ bias,
                                              float* __restrict__ C, int t, int R, int ncols,
                                              int w_ld, int grouped, int relu, long out_bs,
                                              long out_rs) {
    __shared__ float As[32][33];
    __shared__ float Ws[32][68];
    const int tid = threadIdx.x;
    const int tile_j = blockIdx.x * 64;
    const int tile_r = blockIdx.y * 32;
    const float* Wt = W;
    int jbase = tile_j;
    if (grouped) { Wt = W + (size_t)(tile_j >> 9) * kE * kE; jbase = tile_j & 511; }
    const int tx = tid & 15, ty = tid >> 4;
    float acc[2][4] = {{0.f, 0.f, 0.f, 0.f}, {0.f, 0.f, 0.f, 0.f}};
    for (int k0 = 0; k0 < kE; k0 += 32) {
#pragma unroll
        for (int p = tid; p < 32 * 32; p += 256) {
            int rr = p >> 5, cc = p & 31;
            int r = tile_r + rr;
            float v = 0.f;
            if (r < R) {
                int b = r / t, s = r - b * t;
                v = A[(size_t)(b * kS + s) * kE + k0 + cc];
            }
            As[rr][cc] = v;
        }
#pragma unroll
        for (int p = tid; p < 32 * 64; p += 256) {
            int kk = p >> 6, jj = p & 63;
            float v = 0.f;
            if (tile_j + jj < ncols) v = Wt[(size_t)(k0 + kk) * w_ld + jbase + jj];
            Ws[kk][jj] = v;
        }
        __syncthreads();
#pragma unroll
        for (int kk = 0; kk < 32; ++kk) {
            float a0v = As[ty * 2 + 0][kk];
            float a1v = As[ty * 2 + 1][kk];
            const float4 wv = *reinterpret_cast<const float4*>(&Ws[kk][tx * 4]);
            acc[0][0] = fmaf(a0v, wv.x, acc[0][0]);
            acc[0][1] = fmaf(a0v, wv.y, acc[0][1]);
            acc[0][2] = fmaf(a0v, wv.z, acc[0][2]);
            acc[0][3] = fmaf(a0v, wv.w, acc[0][3]);
            acc[1][0] = fmaf(a1v, wv.x, acc[1][0]);
            acc[1][1] = fmaf(a1v, wv.y, acc[1][1]);
            acc[1][2] = fmaf(a1v, wv.z, acc[1][2]);
            acc[1][3] = fmaf(a1v, wv.w, acc[1][3]);
        }
        __syncthreads();
    }
#pragma unroll
    for (int i = 0; i < 2; ++i) {
        int r = tile_r + ty * 2 + i;
        if (r >= R) continue;
        int b = r / t, s = r - b * t;
        float* Crow = C + (size_t)b * out_bs + (size_t)s * out_rs;
#pragma unroll
        for (int q = 0; q < 4; ++q) {
            int j = tile_j + tx * 4 + q;
            if (j >= ncols) continue;
            float v = acc[i][q] + bias[j];
            if (relu) v = fmaxf(v, 0.f);
            Crow[j] = v;
        }
    }
}

// ---------------- logits: grid (157), 64 cols/block, all 32 batch rows in LDS ----------------
__global__ __launch_bounds__(256) void logits_k(const float* __restrict__ act3,
                                                const float* __restrict__ softW,
                                                const float* __restrict__ softb,
                                                float* __restrict__ logits, int tokm1) {
    __shared__ float xs[kB][kE];  // 64KB exactly — nothing else static here
    int tid = threadIdx.x;
    for (int p = tid; p < kB * kE; p += 256) {
        int bb = p >> 9, k = p & 511;
        xs[bb][k] = act3[(size_t)(bb * kS + tokm1) * kE + k];
    }
    __syncthreads();
    const int tx = tid & 31, ty = tid >> 5;  // ty 0..7 -> rows 4ty..4ty+3
    int j0 = blockIdx.x * 64 + 2 * tx;
    int j0c = (j0 + 1 < kV) ? j0 : (kV - 2);  // clamp for safe loads
    float acc[4][2];
#pragma unroll
    for (int r = 0; r < 4; ++r) { acc[r][0] = softb[j0c]; acc[r][1] = softb[j0c + 1]; }
#pragma unroll 4
    for (int k = 0; k < kE; ++k) {
        const float2 wv = *(const float2*)(softW + (size_t)k * kV + j0c);
#pragma unroll
        for (int r = 0; r < 4; ++r) {
            float xv = xs[4 * ty + r][k];
            acc[r][0] = fmaf(xv, wv.x, acc[r][0]);
            acc[r][1] = fmaf(xv, wv.y, acc[r][1]);
        }
    }
    if (j0 + 1 < kV) {
#pragma unroll
        for (int r = 0; r < 4; ++r) {
            logits[(size_t)(4 * ty + r) * kV + j0] = acc[r][0];
            logits[(size_t)(4 * ty + r) * kV + j0 + 1] = acc[r][1];
        }
    } else if (j0 < kV) {
#pragma unroll
        for (int r = 0; r < 4; ++r) logits[(size_t)(4 * ty + r) * kV + j0] = acc[r][0];
    }
}

// ---------------- softmax + argmax + probs + Y row + qkv0 row ----------------
__global__ __launch_bounds__(256) void softargmax_k(const float* __restrict__ logits,
                                                    float* __restrict__ outp,
                                                    const float* __restrict__ emb,
                                                    const float* __restrict__ pe_t,
                                                    float* __restrict__ Y,
                                                    const float* __restrict__ Wq0,
                                                    const float* __restrict__ bq0,
                                                    float* __restrict__ qkv0, int tok) {
    __shared__ float redf[4];
    __shared__ int redi[4];
    __shared__ float ys[kE];
    int b = blockIdx.x, tid = threadIdx.x;
    const float* lg = logits + (size_t)b * kV;
    float m = -3.4e38f;
    int mi = 0;
    for (int j = tid; j < kV; j += 256) {
        float v = lg[j];
        if (v > m) { m = v; mi = j; }
    }
#pragma unroll
    for (int o = 32; o > 0; o >>= 1) {
        float m2 = __shfl_xor(m, o);
        int i2 = __shfl_xor(mi, o);
        if (m2 > m || (m2 == m && i2 < mi)) { m = m2; mi = i2; }
    }
    int wid = tid >> 6;
    if ((tid & 63) == 0) { redf[wid] = m; redi[wid] = mi; }
    __syncthreads();
    m = redf[0]; mi = redi[0];
#pragma unroll
    for (int wv = 1; wv < 4; ++wv) {
        if (redf[wv] > m || (redf[wv] == m && redi[wv] < mi)) { m = redf[wv]; mi = redi[wv]; }
    }
    __syncthreads();
    float ssum = 0.f;
    for (int j = tid; j < kV; j += 256) ssum += expf(lg[j] - m);
    {
#pragma unroll
        for (int o = 32; o > 0; o >>= 1) ssum += __shfl_xor(ssum, o);
        if ((tid & 63) == 0) redf[wid] = ssum;
        __syncthreads();
        ssum = redf[0] + redf[1] + redf[2] + redf[3];
    }
    float inv = 1.f / ssum;
    float* orow = outp + (size_t)b * ((size_t)kS * kV);
    for (int j = tid; j < kV; j += 256) orow[j] = expf(lg[j] - m) * inv;
    const float* erow = emb + (size_t)mi * kE;
    float* yrow = Y + (size_t)(b * kS + tok) * kE;
    for (int j = tid; j < kE; j += 256) {
        float v = erow[j] + pe_t[j];
        yrow[j] = v;
        ys[j] = v;
    }
    __syncthreads();
#pragma unroll
    for (int mq = 0; mq < 6; ++mq) {
        int j = tid + 256 * mq;
        const float* Wc = Wq0 + (size_t)(j >> 9) * (kE * kE) + (j & 511);
        float acc = bq0[j];
        for (int k = 0; k < kE; ++k) acc = fmaf(ys[k], Wc[(size_t)k * kE], acc);
        qkv0[(size_t)(b * kS + tok) * kQ + j] = acc;
    }
}

// ---------------- host ----------------
extern "C" void kernel_launch(void* const* d_in, const int* in_sizes, int n_in, void* d_out,
                              int out_size, void* d_ws, size_t ws_size, hipStream_t stream) {
    const float* noise = (const float*)d_in[0];
    const float* W_in = (const float*)d_in[1];
    const float* b_in = (const float*)d_in[2];
    const float* emb = (const float*)d_in[3];
    const float* Wsa = (const float*)d_in[4];
    const float* bsa = (const float*)d_in[5];
    const float* Wca = (const float*)d_in[6];
    const float* bca = (const float*)d_in[7];
    const float* Wff = (const float*)d_in[8];
    const float* bff = (const float*)d_in[9];
    const float* ln_g = (const float*)d_in[10];
    const float* ln_b = (const float*)d_in[11];
    const float* softW = (const float*)d_in[12];
    const float* softb = (const float*)d_in[13];
    float* out = (float*)d_out;
    (void)d_ws; (void)ws_size; (void)in_sizes; (void)n_in; (void)out_size;

    float *w_, *pe_, *Y_, *qkvb_, *actb_, *lg_, *U_, *a0_, *G_, *c0_;
    hipGetSymbolAddress((void**)&w_, HIP_SYMBOL(g_w));
    hipGetSymbolAddress((void**)&pe_, HIP_SYMBOL(g_pe));
    hipGetSymbolAddress((void**)&Y_, HIP_SYMBOL(g_Y));
    hipGetSymbolAddress((void**)&qkvb_, HIP_SYMBOL(g_qkvbuf));
    hipGetSymbolAddress((void**)&actb_, HIP_SYMBOL(g_actb));
    hipGetSymbolAddress((void**)&lg_, HIP_SYMBOL(g_logits));
    hipGetSymbolAddress((void**)&U_, HIP_SYMBOL(g_U));
    hipGetSymbolAddress((void**)&a0_, HIP_SYMBOL(g_a0));
    hipGetSymbolAddress((void**)&G_, HIP_SYMBOL(g_G));
    hipGetSymbolAddress((void**)&c0_, HIP_SYMBOL(g_c0));

    float* qb[kNB];
    float* ab[kNB];
    for (int n = 0; n < kNB; ++n) {
        qb[n] = qkvb_ + (size_t)n * (kB * kS * kQ);
        ab[n] = actb_ + (size_t)n * (kB * kS * kE);
    }

    dim3 blk(256);
    hipLaunchKernelGGL(onehot_k, dim3((kB * kV + 255) / 256), blk, 0, stream, out);
    hipLaunchKernelGGL(pe_k, dim3(kS * kE / 256), blk, 0, stream, pe_);
    hipLaunchKernelGGL(compute_w_k, dim3(1), dim3(1024), 0, stream, noise, W_in, b_in, w_);
    hipLaunchKernelGGL(initY_k, dim3(kB), blk, 0, stream, emb, pe_, Y_, Wsa, bsa, qb[0]);
    hipLaunchKernelGGL(precross_k, dim3(kNB), blk, 0, stream, Wca, bca, U_, a0_, G_, c0_);

    for (int tok = 1; tok < kS; ++tok) {
        const int t = tok;
        const int R = kB * t;
        const int nch = (t + ROWS - 1) / ROWS;
        for (int n = 0; n < kNB; ++n) {
            const float* in_res = (n == 0) ? Y_ : ab[n - 1];
            const float* Wn = Wsa + (size_t)n * 4 * kE * kE;
            const float* bn = bsa + (size_t)n * 4 * kE;
            const float* Wf = Wff + (size_t)n * 2 * kE * kE;
            const float* bf = bff + (size_t)n * 2 * kE;
            hipLaunchKernelGGL(tail8_k, dim3(kB, nch), blk, 0, stream,
                               qb[n], in_res,
                               Wn + 3 * kE * kE, bn + 3 * kE,
                               ln_g + (size_t)(n * 3 + 0) * kE, ln_b + (size_t)(n * 3 + 0) * kE,
                               U_ + n * kE * kH, a0_ + n * kH, G_ + n * kH * kE, c0_ + n * kE,
                               ln_g + (size_t)(n * 3 + 1) * kE, ln_b + (size_t)(n * 3 + 1) * kE,
                               Wf, bf, Wf + kE * kE, bf + kE,
                               ln_g + (size_t)(n * 3 + 2) * kE, ln_b + (size_t)(n * 3 + 2) * kE,
                               w_, ab[n], t);
            if (n < 3) {
                hipLaunchKernelGGL(gemm_k, dim3(24, (R + 31) / 32), blk, 0, stream, ab[n],
                                   Wsa + (size_t)(n + 1) * 4 * kE * kE,
                                   bsa + (size_t)(n + 1) * 4 * kE, qb[n + 1], t, R, kQ, kE, 1, 0,
                                   (long)(kS * kQ), (long)kQ);
            }
        }
        hipLaunchKernelGGL(logits_k, dim3(157), blk, 0, stream, ab[3], softW, softb, lg_,
                           tok - 1);
        hipLaunchKernelGGL(softargmax_k, dim3(kB), blk, 0, stream, lg_,
                           out + (size_t)tok * kV, emb, pe_ + (size_t)tok * kE, Y_, Wsa, bsa,
                           qb[0], tok);
    }
}

// Round 4
// 22952.539 us; speedup vs baseline: 2.2687x; 1.4439x over previous
//
#include <hip/hip_runtime.h>
#include <cmath>

constexpr int kB = 32, kS = 32, kE = 512, kH = 8, kV = 10000, kNB = 4;
constexpr int kQ = 3 * kE;  // 1536
constexpr int ROWS = 8;     // rows per tail block

// ---------------- device scratch ----------------
__device__ float g_w[kB * kS];
__device__ float g_pe[kS * kE];
__device__ float g_Y[kB * kS * kE];
__device__ float g_qkvbuf[kNB][kB * kS * kQ];
__device__ float g_actb[kNB][kB * kS * kE];
__device__ float g_logits[kB * kV];
__device__ float g_U[kNB * kE * kH];
__device__ float g_a0[kNB * kH];
__device__ float g_G[kNB * kH * kE];
__device__ float g_c0[kNB * kE];

// ---------------- setup kernels ----------------
__global__ void onehot_k(float* __restrict__ out) {
    int i = blockIdx.x * 256 + threadIdx.x;
    if (i >= kB * kV) return;
    int b = i / kV, v = i - b * kV;
    out[(size_t)b * kS * kV + v] = (v == 0) ? 1.f : 0.f;
}

__global__ void pe_k(float* __restrict__ pe) {
    int i = blockIdx.x * 256 + threadIdx.x;  // < kS*kE
    int s = i >> 9, e = i & 511;
    int base = e & ~1;
    float div = expf((float)base * (-logf(10000.f) / (float)kE));
    float ang = (float)s * div;
    pe[i] = (e & 1) ? cosf(ang) : sinf(ang);
}

__global__ void compute_w_k(const float* __restrict__ noise, const float* __restrict__ W_in,
                            const float* __restrict__ b_in, float* __restrict__ w) {
    __shared__ float X[kB * kS], T[kB * kS];
    int tid = threadIdx.x;  // 1024
    X[tid] = noise[tid];
    __syncthreads();
    int r = tid >> 5, c = tid & 31;
    float acc = b_in[c];
    for (int k = 0; k < 32; ++k) acc = fmaf(X[r * 32 + k], W_in[k * 32 + c], acc);
    T[tid] = acc;
    __syncthreads();
    acc = b_in[32 + c];
    for (int k = 0; k < 32; ++k) acc = fmaf(T[r * 32 + k], W_in[1024 + k * 32 + c], acc);
    w[tid] = acc;
}

// Y row 0 = emb[0]+pe[0]; also qkv0 row 0. One block per batch.
__global__ __launch_bounds__(256) void initY_k(const float* __restrict__ emb,
                                               const float* __restrict__ pe,
                                               float* __restrict__ Y,
                                               const float* __restrict__ Wq0,
                                               const float* __restrict__ bq0,
                                               float* __restrict__ qkv0) {
    __shared__ float ys[kE];
    int b = blockIdx.x, tid = threadIdx.x;
    for (int j = tid; j < kE; j += 256) {
        float v = emb[j] + pe[j];
        Y[(size_t)(b * kS) * kE + j] = v;
        ys[j] = v;
    }
    __syncthreads();
#pragma unroll
    for (int m = 0; m < 6; ++m) {
        int j = tid + 256 * m;
        const float* Wc = Wq0 + (size_t)(j >> 9) * (kE * kE) + (j & 511);
        float acc = bq0[j];
        for (int k = 0; k < kE; ++k) acc = fmaf(ys[k], Wc[(size_t)k * kE], acc);
        qkv0[(size_t)(b * kS) * kQ + j] = acc;
    }
}

// Precompute reduced cross-attn operators.
__global__ __launch_bounds__(256) void precross_k(const float* __restrict__ Wca,
                                                  const float* __restrict__ bca,
                                                  float* __restrict__ U, float* __restrict__ a0,
                                                  float* __restrict__ G, float* __restrict__ c0) {
    int n = blockIdx.x;
    const float* Wq = Wca + (size_t)n * 4 * kE * kE;
    const float* Wk = Wq + kE * kE;
    const float* Wv = Wk + kE * kE;
    const float* Wo = Wv + kE * kE;
    const float* bq = bca + n * 4 * kE;
    const float* bv = bq + 2 * kE;
    const float* bo = bq + 3 * kE;
    __shared__ float ck[kE], cv[kE];
    int tid = threadIdx.x;
    for (int j = tid; j < kE; j += 256) {
        float s1 = 0.f, s2 = 0.f;
        for (int e = 0; e < kE; ++e) { s1 += Wk[e * kE + j]; s2 += Wv[e * kE + j]; }
        ck[j] = s1; cv[j] = s2;
    }
    __syncthreads();
    for (int p = tid; p < kE * kH; p += 256) {
        int e = p >> 3, h = p & 7;
        float acc = 0.f;
        for (int d = 0; d < 64; ++d) acc = fmaf(Wq[e * kE + h * 64 + d], ck[h * 64 + d], acc);
        U[n * kE * kH + p] = acc;
    }
    if (tid < kH) {
        float acc = 0.f;
        for (int d = 0; d < 64; ++d) acc = fmaf(bq[tid * 64 + d], ck[tid * 64 + d], acc);
        a0[n * kH + tid] = acc;
    }
    for (int p = tid; p < kH * kE; p += 256) {
        int h = p >> 9, j = p & 511;
        float acc = 0.f;
        for (int d = 0; d < 64; ++d) acc = fmaf(cv[h * 64 + d], Wo[(h * 64 + d) * kE + j], acc);
        G[n * kH * kE + p] = acc;
    }
    for (int j = tid; j < kE; j += 256) {
        float acc = bo[j];
        for (int e = 0; e < kE; ++e) acc = fmaf(bv[e], Wo[e * kE + j], acc);
        c0[n * kE + j] = acc;
    }
}

// ---------------- 512-thread (8-wave) row reductions ----------------
__device__ __forceinline__ void rowsum8_512(float v[ROWS], float (*red)[ROWS], float out[ROWS]) {
    int lane = threadIdx.x & 63, w = threadIdx.x >> 6;
#pragma unroll
    for (int i = 0; i < ROWS; ++i) {
        float s = v[i];
#pragma unroll
        for (int o = 32; o > 0; o >>= 1) s += __shfl_xor(s, o);
        v[i] = s;
    }
    if (lane == 0) {
#pragma unroll
        for (int i = 0; i < ROWS; ++i) red[w][i] = v[i];
    }
    __syncthreads();
#pragma unroll
    for (int i = 0; i < ROWS; ++i) {
        float s = 0.f;
#pragma unroll
        for (int w2 = 0; w2 < 8; ++w2) s += red[w2][i];
        out[i] = s;
    }
    __syncthreads();
}

// In-place LN of 8 rows; each thread holds col j of every row in val[].
__device__ __forceinline__ void ln8_512(float val[ROWS], const float* __restrict__ g,
                                        const float* __restrict__ bb, float (*red)[ROWS], int j) {
    float s[ROWS], mean[ROWS], var[ROWS];
#pragma unroll
    for (int i = 0; i < ROWS; ++i) s[i] = val[i];
    rowsum8_512(s, red, mean);
#pragma unroll
    for (int i = 0; i < ROWS; ++i) {
        mean[i] *= (1.f / (float)kE);
        val[i] -= mean[i];
        s[i] = val[i] * val[i];
    }
    rowsum8_512(s, red, var);
    float gj = g[j], bj = bb[j];
#pragma unroll
    for (int i = 0; i < ROWS; ++i) {
        float rstd = rsqrtf(var[i] * (1.f / (float)kE) + 1e-5f);
        val[i] = gj * val[i] * rstd + bj;
    }
}

// GEMM phase: out[i][j] = sum_k in[i][k]*W[k][j] via 4-way k-split + LDS reduce.
// kg = tid>>7 (k range of 128), jt = tid&127 (4 cols). VALU-bound: 128 fma per 4-k chunk.
__device__ __forceinline__ void gemm_phase(const float (*in)[kE], const float* __restrict__ W,
                                           float (*out)[kE], int kg, int jt) {
    float acc[ROWS][4];
#pragma unroll
    for (int i = 0; i < ROWS; ++i)
#pragma unroll
        for (int c = 0; c < 4; ++c) acc[i][c] = 0.f;
    const int kbase = kg * 128;
    const int j4 = jt * 4;
#pragma unroll 2
    for (int kk = 0; kk < 128; kk += 4) {
        const float4 wv0 = *(const float4*)(W + (size_t)(kbase + kk + 0) * kE + j4);
        const float4 wv1 = *(const float4*)(W + (size_t)(kbase + kk + 1) * kE + j4);
        const float4 wv2 = *(const float4*)(W + (size_t)(kbase + kk + 2) * kE + j4);
        const float4 wv3 = *(const float4*)(W + (size_t)(kbase + kk + 3) * kE + j4);
#pragma unroll
        for (int i = 0; i < ROWS; ++i) {
            const float4 av = *(const float4*)(&in[i][kbase + kk]);
            acc[i][0] = fmaf(av.x, wv0.x, acc[i][0]);
            acc[i][0] = fmaf(av.y, wv1.x, acc[i][0]);
            acc[i][0] = fmaf(av.z, wv2.x, acc[i][0]);
            acc[i][0] = fmaf(av.w, wv3.x, acc[i][0]);
            acc[i][1] = fmaf(av.x, wv0.y, acc[i][1]);
            acc[i][1] = fmaf(av.y, wv1.y, acc[i][1]);
            acc[i][1] = fmaf(av.z, wv2.y, acc[i][1]);
            acc[i][1] = fmaf(av.w, wv3.y, acc[i][1]);
            acc[i][2] = fmaf(av.x, wv0.z, acc[i][2]);
            acc[i][2] = fmaf(av.y, wv1.z, acc[i][2]);
            acc[i][2] = fmaf(av.z, wv2.z, acc[i][2]);
            acc[i][2] = fmaf(av.w, wv3.z, acc[i][2]);
            acc[i][3] = fmaf(av.x, wv0.w, acc[i][3]);
            acc[i][3] = fmaf(av.y, wv1.w, acc[i][3]);
            acc[i][3] = fmaf(av.z, wv2.w, acc[i][3]);
            acc[i][3] = fmaf(av.w, wv3.w, acc[i][3]);
        }
    }
    // deterministic sequential k-group reduce into out
    if (kg == 0) {
#pragma unroll
        for (int i = 0; i < ROWS; ++i)
            *(float4*)(&out[i][j4]) = make_float4(acc[i][0], acc[i][1], acc[i][2], acc[i][3]);
    }
    __syncthreads();
#pragma unroll
    for (int r = 1; r < 4; ++r) {
        if (kg == r) {
#pragma unroll
            for (int i = 0; i < ROWS; ++i) {
                float4 c = *(float4*)(&out[i][j4]);
                c.x += acc[i][0]; c.y += acc[i][1]; c.z += acc[i][2]; c.w += acc[i][3];
                *(float4*)(&out[i][j4]) = c;
            }
        }
        __syncthreads();
    }
}

// ---------------- fused tail: attn+proj+LN+cross+crossLN+FF1+FF2+LN ----------------
// grid (kB, ceil(t/8)), 512 threads (8 waves).
__global__ __launch_bounds__(512) void tail8v2_k(
    const float* __restrict__ qkv_cur, const float* __restrict__ in_res,
    const float* __restrict__ Wo, const float* __restrict__ bo,
    const float* __restrict__ g0, const float* __restrict__ lb0,
    const float* __restrict__ Um, const float* __restrict__ a0m,
    const float* __restrict__ Gm, const float* __restrict__ c0m,
    const float* __restrict__ g1, const float* __restrict__ lb1,
    const float* __restrict__ W1, const float* __restrict__ fb1,
    const float* __restrict__ W2, const float* __restrict__ fb2,
    const float* __restrict__ g2, const float* __restrict__ lb2,
    const float* __restrict__ wvec, float* __restrict__ act_out, int t) {
    __shared__ float bufA[ROWS][kE];       // 16KB: activations
    __shared__ float bufC[ROWS][kE];       // 16KB: gemm-phase raw output
    __shared__ float Us[kE * kH];          // 16KB
    __shared__ float att_s[8][kS];
    __shared__ float alp[ROWS][kH][4];
    __shared__ float om_s[ROWS][kH];
    __shared__ float w_s[kS];
    __shared__ float red[8][ROWS];

    const int b = blockIdx.x;
    const int r0 = blockIdx.y * ROWS;
    const int tid = threadIdx.x;
    const int lane = tid & 63, wid = tid >> 6;  // 8 waves
    int rr[ROWS]; bool valid[ROWS];
#pragma unroll
    for (int i = 0; i < ROWS; ++i) {
        int r = r0 + i;
        valid[i] = (r < t);
        rr[i] = valid[i] ? r : (t - 1);
    }

    // stage Q rows into bufA, U into Us, w
    for (int p = tid; p < ROWS * kE; p += 512) {
        int i = p >> 9, d = p & 511;
        bufA[i][d] = qkv_cur[(size_t)(b * kS + rr[i]) * kQ + d];
    }
    for (int p = tid; p < kE * kH; p += 512) Us[p] = Um[p];
    if (tid < t) w_s[tid] = wvec[b * kS + tid];
    __syncthreads();

    // ---- self-attention: wave wid owns row wid ----
    {
        const int i = wid;
        for (int h = 0; h < kH; ++h) {
            float sc = -3.0e38f;
            if (lane < t) {
                const float* Kr = qkv_cur + (size_t)(b * kS + lane) * kQ + kE + h * 64;
                float a = 0.f;
#pragma unroll
                for (int d4 = 0; d4 < 16; ++d4) {
                    const float4 kv = *(const float4*)(Kr + d4 * 4);
                    const float4 qv = *(const float4*)(&bufA[i][h * 64 + d4 * 4]);
                    a = fmaf(qv.x, kv.x, a); a = fmaf(qv.y, kv.y, a);
                    a = fmaf(qv.z, kv.z, a); a = fmaf(qv.w, kv.w, a);
                }
                sc = a * 0.125f;
            }
            float m = sc;
#pragma unroll
            for (int o = 32; o > 0; o >>= 1) m = fmaxf(m, __shfl_xor(m, o));
            float e = (lane < t) ? expf(sc - m) : 0.f;
            float ss = e;
#pragma unroll
            for (int o = 32; o > 0; o >>= 1) ss += __shfl_xor(ss, o);
            if (lane < t) att_s[wid][lane] = e / ss;
            float acc = 0.f;
            const float* Vb = qkv_cur + (size_t)(b * kS) * kQ + 2 * kE + h * 64 + lane;
            for (int k = 0; k < t; ++k) acc = fmaf(att_s[wid][k], Vb[(size_t)k * kQ], acc);
            bufA[i][h * 64 + lane] = acc;  // safe: own row, head slice dead after its score
        }
    }
    __syncthreads();

    const int kg = tid >> 7, jt = tid & 127;
    float val[ROWS], hreg[ROWS], h2reg[ROWS];

    // ---- proj GEMM + residual + LN -> h (bufA, hreg) ----
    gemm_phase(bufA, Wo, bufC, kg, jt);
    {
        float btid = bo[tid];
#pragma unroll
        for (int i = 0; i < ROWS; ++i)
            val[i] = bufC[i][tid] + btid + in_res[(size_t)(b * kS + rr[i]) * kE + tid];
        ln8_512(val, g0, lb0, red, tid);
#pragma unroll
        for (int i = 0; i < ROWS; ++i) { hreg[i] = val[i]; bufA[i][tid] = val[i]; }
    }
    __syncthreads();

    // ---- reduced cross-attn: alpha partials (256 threads), omega (64 threads) ----
    if (tid < 256) {
        int i = tid >> 5, h = (tid >> 2) & 7, c = tid & 3;
        float a = 0.f;
        for (int e = c * 128; e < c * 128 + 128; ++e) a = fmaf(bufA[i][e], Us[e * kH + h], a);
        alp[i][h][c] = a;
    }
    __syncthreads();
    if (tid < 64) {
        int i = tid >> 3, h = tid & 7;
        float a = a0m[h] + alp[i][h][0] + alp[i][h][1] + alp[i][h][2] + alp[i][h][3];
        a *= 0.125f;
        float mm = -3.0e38f;
        for (int s = 0; s < t; ++s) mm = fmaxf(mm, a * w_s[s]);
        float se = 0.f, sw = 0.f;
        for (int s = 0; s < t; ++s) {
            float ex = expf(a * w_s[s] - mm);
            se += ex;
            sw = fmaf(ex, w_s[s], sw);
        }
        om_s[i][h] = sw / se;
    }
    __syncthreads();

    // ---- crossout + residual(h) + LN -> h2 (bufA, h2reg) ----
    {
        float ctid = c0m[tid];
#pragma unroll
        for (int i = 0; i < ROWS; ++i) {
            float v = ctid + hreg[i];
#pragma unroll
            for (int h = 0; h < kH; ++h) v = fmaf(om_s[i][h], Gm[h * kE + tid], v);
            val[i] = v;
        }
        ln8_512(val, g1, lb1, red, tid);
#pragma unroll
        for (int i = 0; i < ROWS; ++i) { h2reg[i] = val[i]; bufA[i][tid] = val[i]; }
    }
    __syncthreads();

    // ---- FF1 GEMM + relu -> bufA ----
    gemm_phase(bufA, W1, bufC, kg, jt);
    {
        float btid = fb1[tid];
#pragma unroll
        for (int i = 0; i < ROWS; ++i) val[i] = fmaxf(bufC[i][tid] + btid, 0.f);
#pragma unroll
        for (int i = 0; i < ROWS; ++i) bufA[i][tid] = val[i];
    }
    __syncthreads();

    // ---- FF2 GEMM + residual(h2) + LN -> act_out ----
    gemm_phase(bufA, W2, bufC, kg, jt);
    {
        float btid = fb2[tid];
#pragma unroll
        for (int i = 0; i < ROWS; ++i) val[i] = bufC[i][tid] + btid + h2reg[i];
        ln8_512(val, g2, lb2, red, tid);
#pragma unroll
        for (int i = 0; i < ROWS; ++i)
            if (valid[i]) act_out[(size_t)(b * kS + r0 + i) * kE + tid] = val[i];
    }
}

// ---------------- tiled fp32 GEMM (verified): C = A@W + bias ----------------
__global__ __launch_bounds__(256) void gemm_k(const float* __restrict__ A,
                                              const float* __restrict__ W,
                                              const float* __restrict__ bias,
                                              float* __restrict__ C, int t, int R, int ncols,
                                              int w_ld, int grouped, int relu, long out_bs,
                                              long out_rs) {
    __shared__ float As[32][33];
    __shared__ float Ws[32][68];
    const int tid = threadIdx.x;
    const int tile_j = blockIdx.x * 64;
    const int tile_r = blockIdx.y * 32;
    const float* Wt = W;
    int jbase = tile_j;
    if (grouped) { Wt = W + (size_t)(tile_j >> 9) * kE * kE; jbase = tile_j & 511; }
    const int tx = tid & 15, ty = tid >> 4;
    float acc[2][4] = {{0.f, 0.f, 0.f, 0.f}, {0.f, 0.f, 0.f, 0.f}};
    for (int k0 = 0; k0 < kE; k0 += 32) {
#pragma unroll
        for (int p = tid; p < 32 * 32; p += 256) {
            int rr = p >> 5, cc = p & 31;
            int r = tile_r + rr;
            float v = 0.f;
            if (r < R) {
                int b = r / t, s = r - b * t;
                v = A[(size_t)(b * kS + s) * kE + k0 + cc];
            }
            As[rr][cc] = v;
        }
#pragma unroll
        for (int p = tid; p < 32 * 64; p += 256) {
            int kk = p >> 6, jj = p & 63;
            float v = 0.f;
            if (tile_j + jj < ncols) v = Wt[(size_t)(k0 + kk) * w_ld + jbase + jj];
            Ws[kk][jj] = v;
        }
        __syncthreads();
#pragma unroll
        for (int kk = 0; kk < 32; ++kk) {
            float a0v = As[ty * 2 + 0][kk];
            float a1v = As[ty * 2 + 1][kk];
            const float4 wv = *reinterpret_cast<const float4*>(&Ws[kk][tx * 4]);
            acc[0][0] = fmaf(a0v, wv.x, acc[0][0]);
            acc[0][1] = fmaf(a0v, wv.y, acc[0][1]);
            acc[0][2] = fmaf(a0v, wv.z, acc[0][2]);
            acc[0][3] = fmaf(a0v, wv.w, acc[0][3]);
            acc[1][0] = fmaf(a1v, wv.x, acc[1][0]);
            acc[1][1] = fmaf(a1v, wv.y, acc[1][1]);
            acc[1][2] = fmaf(a1v, wv.z, acc[1][2]);
            acc[1][3] = fmaf(a1v, wv.w, acc[1][3]);
        }
        __syncthreads();
    }
#pragma unroll
    for (int i = 0; i < 2; ++i) {
        int r = tile_r + ty * 2 + i;
        if (r >= R) continue;
        int b = r / t, s = r - b * t;
        float* Crow = C + (size_t)b * out_bs + (size_t)s * out_rs;
#pragma unroll
        for (int q = 0; q < 4; ++q) {
            int j = tile_j + tx * 4 + q;
            if (j >= ncols) continue;
            float v = acc[i][q] + bias[j];
            if (relu) v = fmaxf(v, 0.f);
            Crow[j] = v;
        }
    }
}

// ---------------- logits: grid (157), 64 cols/block, all 32 batch rows in LDS ----------------
__global__ __launch_bounds__(256) void logits_k(const float* __restrict__ act3,
                                                const float* __restrict__ softW,
                                                const float* __restrict__ softb,
                                                float* __restrict__ logits, int tokm1) {
    __shared__ float xs[kB][kE];  // 64KB
    int tid = threadIdx.x;
    for (int p = tid; p < kB * kE; p += 256) {
        int bb = p >> 9, k = p & 511;
        xs[bb][k] = act3[(size_t)(bb * kS + tokm1) * kE + k];
    }
    __syncthreads();
    const int tx = tid & 31, ty = tid >> 5;
    int j0 = blockIdx.x * 64 + 2 * tx;
    int j0c = (j0 + 1 < kV) ? j0 : (kV - 2);
    float acc[4][2];
#pragma unroll
    for (int r = 0; r < 4; ++r) { acc[r][0] = softb[j0c]; acc[r][1] = softb[j0c + 1]; }
#pragma unroll 4
    for (int k = 0; k < kE; ++k) {
        const float2 wv = *(const float2*)(softW + (size_t)k * kV + j0c);
#pragma unroll
        for (int r = 0; r < 4; ++r) {
            float xv = xs[4 * ty + r][k];
            acc[r][0] = fmaf(xv, wv.x, acc[r][0]);
            acc[r][1] = fmaf(xv, wv.y, acc[r][1]);
        }
    }
    if (j0 + 1 < kV) {
#pragma unroll
        for (int r = 0; r < 4; ++r) {
            logits[(size_t)(4 * ty + r) * kV + j0] = acc[r][0];
            logits[(size_t)(4 * ty + r) * kV + j0 + 1] = acc[r][1];
        }
    } else if (j0 < kV) {
#pragma unroll
        for (int r = 0; r < 4; ++r) logits[(size_t)(4 * ty + r) * kV + j0] = acc[r][0];
    }
}

// ---------------- softmax + argmax + probs + Y row ----------------
__global__ __launch_bounds__(256) void softargmax_k(const float* __restrict__ logits,
                                                    float* __restrict__ outp,
                                                    const float* __restrict__ emb,
                                                    const float* __restrict__ pe_t,
                                                    float* __restrict__ Y, int tok) {
    __shared__ float redf[4];
    __shared__ int redi[4];
    int b = blockIdx.x, tid = threadIdx.x;
    const float* lg = logits + (size_t)b * kV;
    float m = -3.4e38f;
    int mi = 0;
    for (int j = tid; j < kV; j += 256) {
        float v = lg[j];
        if (v > m) { m = v; mi = j; }
    }
#pragma unroll
    for (int o = 32; o > 0; o >>= 1) {
        float m2 = __shfl_xor(m, o);
        int i2 = __shfl_xor(mi, o);
        if (m2 > m || (m2 == m && i2 < mi)) { m = m2; mi = i2; }
    }
    int wid = tid >> 6;
    if ((tid & 63) == 0) { redf[wid] = m; redi[wid] = mi; }
    __syncthreads();
    m = redf[0]; mi = redi[0];
#pragma unroll
    for (int wv = 1; wv < 4; ++wv) {
        if (redf[wv] > m || (redf[wv] == m && redi[wv] < mi)) { m = redf[wv]; mi = redi[wv]; }
    }
    __syncthreads();
    float ssum = 0.f;
    for (int j = tid; j < kV; j += 256) ssum += expf(lg[j] - m);
    {
#pragma unroll
        for (int o = 32; o > 0; o >>= 1) ssum += __shfl_xor(ssum, o);
        if ((tid & 63) == 0) redf[wid] = ssum;
        __syncthreads();
        ssum = redf[0] + redf[1] + redf[2] + redf[3];
    }
    float inv = 1.f / ssum;
    float* orow = outp + (size_t)b * ((size_t)kS * kV);
    for (int j = tid; j < kV; j += 256) orow[j] = expf(lg[j] - m) * inv;
    const float* erow = emb + (size_t)mi * kE;
    float* yrow = Y + (size_t)(b * kS + tok) * kE;
    for (int j = tid; j < kE; j += 256) yrow[j] = erow[j] + pe_t[j];
}

// ---------------- qkv0 row for the new token: grid (kB, 6) ----------------
__global__ __launch_bounds__(256) void qkvrow_k(const float* __restrict__ Y,
                                                const float* __restrict__ Wq0,
                                                const float* __restrict__ bq0,
                                                float* __restrict__ qkv0, int tok) {
    __shared__ float ys[kE];
    int b = blockIdx.x, m = blockIdx.y, tid = threadIdx.x;
    const float* yrow = Y + (size_t)(b * kS + tok) * kE;
    ys[tid] = yrow[tid];
    ys[tid + 256] = yrow[tid + 256];
    __syncthreads();
    int j = m * 256 + tid;
    const float* Wc = Wq0 + (size_t)(j >> 9) * (kE * kE) + (j & 511);
    float acc = bq0[j];
#pragma unroll 8
    for (int k = 0; k < kE; ++k) acc = fmaf(ys[k], Wc[(size_t)k * kE], acc);
    qkv0[(size_t)(b * kS + tok) * kQ + j] = acc;
}

// ---------------- host ----------------
extern "C" void kernel_launch(void* const* d_in, const int* in_sizes, int n_in, void* d_out,
                              int out_size, void* d_ws, size_t ws_size, hipStream_t stream) {
    const float* noise = (const float*)d_in[0];
    const float* W_in = (const float*)d_in[1];
    const float* b_in = (const float*)d_in[2];
    const float* emb = (const float*)d_in[3];
    const float* Wsa = (const float*)d_in[4];
    const float* bsa = (const float*)d_in[5];
    const float* Wca = (const float*)d_in[6];
    const float* bca = (const float*)d_in[7];
    const float* Wff = (const float*)d_in[8];
    const float* bff = (const float*)d_in[9];
    const float* ln_g = (const float*)d_in[10];
    const float* ln_b = (const float*)d_in[11];
    const float* softW = (const float*)d_in[12];
    const float* softb = (const float*)d_in[13];
    float* out = (float*)d_out;
    (void)d_ws; (void)ws_size; (void)in_sizes; (void)n_in; (void)out_size;

    float *w_, *pe_, *Y_, *qkvb_, *actb_, *lg_, *U_, *a0_, *G_, *c0_;
    hipGetSymbolAddress((void**)&w_, HIP_SYMBOL(g_w));
    hipGetSymbolAddress((void**)&pe_, HIP_SYMBOL(g_pe));
    hipGetSymbolAddress((void**)&Y_, HIP_SYMBOL(g_Y));
    hipGetSymbolAddress((void**)&qkvb_, HIP_SYMBOL(g_qkvbuf));
    hipGetSymbolAddress((void**)&actb_, HIP_SYMBOL(g_actb));
    hipGetSymbolAddress((void**)&lg_, HIP_SYMBOL(g_logits));
    hipGetSymbolAddress((void**)&U_, HIP_SYMBOL(g_U));
    hipGetSymbolAddress((void**)&a0_, HIP_SYMBOL(g_a0));
    hipGetSymbolAddress((void**)&G_, HIP_SYMBOL(g_G));
    hipGetSymbolAddress((void**)&c0_, HIP_SYMBOL(g_c0));

    float* qb[kNB];
    float* ab[kNB];
    for (int n = 0; n < kNB; ++n) {
        qb[n] = qkvb_ + (size_t)n * (kB * kS * kQ);
        ab[n] = actb_ + (size_t)n * (kB * kS * kE);
    }

    dim3 blk(256);
    hipLaunchKernelGGL(onehot_k, dim3((kB * kV + 255) / 256), blk, 0, stream, out);
    hipLaunchKernelGGL(pe_k, dim3(kS * kE / 256), blk, 0, stream, pe_);
    hipLaunchKernelGGL(compute_w_k, dim3(1), dim3(1024), 0, stream, noise, W_in, b_in, w_);
    hipLaunchKernelGGL(initY_k, dim3(kB), blk, 0, stream, emb, pe_, Y_, Wsa, bsa, qb[0]);
    hipLaunchKernelGGL(precross_k, dim3(kNB), blk, 0, stream, Wca, bca, U_, a0_, G_, c0_);

    for (int tok = 1; tok < kS; ++tok) {
        const int t = tok;
        const int R = kB * t;
        const int nch = (t + ROWS - 1) / ROWS;
        for (int n = 0; n < kNB; ++n) {
            const float* in_res = (n == 0) ? Y_ : ab[n - 1];
            const float* Wn = Wsa + (size_t)n * 4 * kE * kE;
            const float* bn = bsa + (size_t)n * 4 * kE;
            const float* Wf = Wff + (size_t)n * 2 * kE * kE;
            const float* bf = bff + (size_t)n * 2 * kE;
            hipLaunchKernelGGL(tail8v2_k, dim3(kB, nch), dim3(512), 0, stream,
                               qb[n], in_res,
                               Wn + 3 * kE * kE, bn + 3 * kE,
                               ln_g + (size_t)(n * 3 + 0) * kE, ln_b + (size_t)(n * 3 + 0) * kE,
                               U_ + n * kE * kH, a0_ + n * kH, G_ + n * kH * kE, c0_ + n * kE,
                               ln_g + (size_t)(n * 3 + 1) * kE, ln_b + (size_t)(n * 3 + 1) * kE,
                               Wf, bf, Wf + kE * kE, bf + kE,
                               ln_g + (size_t)(n * 3 + 2) * kE, ln_b + (size_t)(n * 3 + 2) * kE,
                               w_, ab[n], t);
            if (n < 3) {
                hipLaunchKernelGGL(gemm_k, dim3(24, (R + 31) / 32), blk, 0, stream, ab[n],
                                   Wsa + (size_t)(n + 1) * 4 * kE * kE,
                                   bsa + (size_t)(n + 1) * 4 * kE, qb[n + 1], t, R, kQ, kE, 1, 0,
                                   (long)(kS * kQ), (long)kQ);
            }
        }
        hipLaunchKernelGGL(logits_k, dim3(157), blk, 0, stream, ab[3], softW, softb, lg_,
                           tok - 1);
        hipLaunchKernelGGL(softargmax_k, dim3(kB), blk, 0, stream, lg_,
                           out + (size_t)tok * kV, emb, pe_ + (size_t)tok * kE, Y_, tok);
        hipLaunchKernelGGL(qkvrow_k, dim3(kB, 6), blk, 0, stream, Y_, Wsa, bsa, qb[0], tok);
    }
}